// Round 15
// baseline (536.481 us; speedup 1.0000x reference)
//
#include <hip/hip_runtime.h>
#include <hip/hip_bf16.h>

#define BB 32
#define NN 32768
#define GG 64
#define KK 32
#define DD 384
#define EPSF 1e-5f
#define FPS_NBLK 8
#define FPS_SL   (NN/FPS_NBLK)

typedef __attribute__((ext_vector_type(8))) short short8;
typedef __attribute__((ext_vector_type(4))) float f32x4;

__device__ __forceinline__ float rn_add(float a, float b){ return __fadd_rn(a,b); }
__device__ __forceinline__ float rn_sub(float a, float b){ return __fsub_rn(a,b); }
__device__ __forceinline__ float rn_mul(float a, float b){ return __fmul_rn(a,b); }

__device__ __forceinline__ unsigned fkey(float d){
  unsigned u = __float_as_uint(d);
  return (u & 0x80000000u) ? ~u : (u | 0x80000000u);
}

__device__ __forceinline__ unsigned short f2bf(float f){
  unsigned u = __float_as_uint(f);
  unsigned r = (u + 0x7FFFu + ((u >> 16) & 1u)) >> 16;
  return (unsigned short)r;
}

#define REP8(X) X(0) X(1) X(2) X(3) X(4) X(5) X(6) X(7)

// ---- module-scope scratch ------------------------------------------------
__device__ float g_center[BB*GG*3];
__device__ int   g_knn[BB*GG*KK];
__device__ float g_w1t[6*64];
__device__ float g_b1[64];
__device__ float g_b2[128];
__device__ float g_b3[384];
__device__ __align__(16) unsigned short g_w2f[8*2*64*8];    // w2 MFMA frags
__device__ __align__(16) unsigned short g_w3f[24*4*64*8];   // w3 MFMA frags
__device__ float g_X[BB*NN];
__device__ float g_Y[BB*NN];
__device__ float g_Z[BB*NN];
__device__ float g_N2[BB*NN];
// fps exchange slots: per (b,sub,parity) a 128B-spaced triple
//   [0]=key (tag|idx in low word), [1]=(x,y) bits, [2]=z bits
__device__ unsigned long long g_slot[BB*FPS_NBLK*2*16];     // 64 KB

// ---------------------------------------------------------------------------
// One-shot AoS -> SoA repack + n2 precompute (bit-exact rn sequence).
// ---------------------------------------------------------------------------
__global__ __launch_bounds__(256) void k_soa(const float* __restrict__ xyz){
  int tid = blockIdx.x * blockDim.x + threadIdx.x;
  int b = tid >> 15;
  int p = tid & (NN - 1);
  const float* s = xyz + (size_t)b*NN*3 + (size_t)p*3;
  float x = s[0], y = s[1], z = s[2];
  g_X[tid] = x;
  g_Y[tid] = y;
  g_Z[tid] = z;
  g_N2[tid] = rn_add(rn_add(rn_mul(x,x), rn_mul(y,y)), rn_mul(z,z));
}

__global__ __launch_bounds__(256) void k_zero(void){
  int tid = blockIdx.x * blockDim.x + threadIdx.x;
  if (tid < BB*FPS_NBLK*2*16) g_slot[tid] = 0ull;
}

// ---------------------------------------------------------------------------
// Weight prep (validated r12): fold BN; w1 transposed f32; w2/w3 bf16 frags.
// ---------------------------------------------------------------------------
__global__ void k_prep(const float* __restrict__ w1, const float* __restrict__ g1, const float* __restrict__ b1, const float* __restrict__ m1, const float* __restrict__ v1,
                       const float* __restrict__ w2, const float* __restrict__ g2, const float* __restrict__ b2, const float* __restrict__ m2, const float* __restrict__ v2,
                       const float* __restrict__ w3, const float* __restrict__ g3, const float* __restrict__ b3, const float* __restrict__ m3, const float* __restrict__ v3){
  int tid = blockIdx.x * blockDim.x + threadIdx.x;
  int nt  = gridDim.x * blockDim.x;
  for (int e = tid; e < 64*6; e += nt){
    int c = e >> 6, o = e & 63;
    float s = g1[o] * rsqrtf(v1[o] + EPSF);
    g_w1t[e] = w1[o*6 + c] * s;
  }
  for (int o = tid; o < 64; o += nt){
    float s = g1[o] * rsqrtf(v1[o] + EPSF);
    g_b1[o] = b1[o] - m1[o]*s;
  }
  for (int o = tid; o < 128; o += nt){
    float s = g2[o] * rsqrtf(v2[o] + EPSF);
    g_b2[o] = b2[o] - m2[o]*s;
  }
  for (int o = tid; o < 384; o += nt){
    float s = g3[o] * rsqrtf(v3[o] + EPSF);
    g_b3[o] = b3[o] - m3[o]*s;
  }
  for (int idx = tid; idx < 8192; idx += nt){
    int e  = idx & 7;
    int l  = (idx >> 3) & 63;
    int kt = (idx >> 9) & 1;
    int ct = idx >> 10;
    int j  = ct*16 + (l & 15);
    int k  = kt*32 + ((l >> 4) << 3) + e;
    float s = g2[j] * rsqrtf(v2[j] + EPSF);
    g_w2f[idx] = f2bf(w2[j*64 + k] * s);
  }
  for (int idx = tid; idx < 49152; idx += nt){
    int e  = idx & 7;
    int l  = (idx >> 3) & 63;
    int kt = (idx >> 9) & 3;
    int ct = idx >> 11;
    int j  = ct*16 + (l & 15);
    int k  = kt*32 + ((l >> 4) << 3) + e;
    float s = g3[j] * rsqrtf(v3[j] + EPSF);
    g_w3f[idx] = f2bf(w3[j*128 + k] * s);
  }
}

// ---------------------------------------------------------------------------
// FPS v7. r14 residual diagnosis: per-iter critical path still carried
// (a) 3 dependent HBM-miss loads of Xb/Yb/Zb[far] (~900cy) and (b) exposed
// LDS latency at 1 wave/SIMD. Changes (selection math identical):
//  - winner COORDS ride the exchange: publisher release-stores
//    {key|tag, (x,y), z}; pollers acquire-load key then read coords (L2).
//  - tagged hot slots, parity-double-buffered: key low word =
//    ((it+1)<<15)|(32767-idx). Tag is constant within a round -> ordering
//    still (max d, tie -> min idx) == numpy argmax. Slot reused every 2
//    iters (>=~4000cy) vs poller's ~300cy read window.
//  - 512 threads (8 pts/thread, dd0..dd7): 2 waves/SIMD hides LDS latency.
// ---------------------------------------------------------------------------
__global__ __launch_bounds__(512)
void k_fps(float* __restrict__ outCenter){
  const int blk = blockIdx.x;
  const int b   = blk & 31;          // batch (XCD co-location, r14-validated)
  const int sub = blk >> 5;          // sub-block 0..7
  const int t   = threadIdx.x;
  const int wv  = t >> 6, ln = t & 63;
  const int base = sub * FPS_SL;
  const float* Xb = g_X + (size_t)b*NN;
  const float* Yb = g_Y + (size_t)b*NN;
  const float* Zb = g_Z + (size_t)b*NN;

  __shared__ float sx[FPS_SL], sy[FPS_SL], szz[FPS_SL];   // 48 KB
  __shared__ unsigned long long skey[8];
  __shared__ int s_far;
  __shared__ float s_cx, s_cy, s_cz;

  #pragma unroll
  for (int i = 0; i < 8; ++i){
    int p = (i << 9) + t;
    sx[p]  = Xb[base + p];
    sy[p]  = Yb[base + p];
    szz[p] = Zb[base + p];
  }
  __syncthreads();

#define DD_DECL(i) float dd##i = 1e10f;
  REP8(DD_DECL)
#undef DD_DECL

  int   far = 0;
  float cx = Xb[0], cy = Yb[0], cz = Zb[0];   // initial centroid (point 0)

  for (int it = 0; ; ++it){
    if (sub == 0 && t == 0){
      float* cw = g_center  + (size_t)(b*GG + it)*3;
      float* co = outCenter + (size_t)(b*GG + it)*3;
      cw[0] = cx; cw[1] = cy; cw[2] = cz;
      co[0] = cx; co[1] = cy; co[2] = cz;
    }
    if (it == GG - 1) break;

    const unsigned long long tag = (unsigned long long)((unsigned)(it + 1) << 15);
    unsigned long long bk = 0ull;
    // ascending i => ascending point idx; key = (fkey(d)<<32)|tag|(32767-p):
    // same-round tag is constant => max key == (max d, tie -> lowest idx).
#define DD_UPD(i) { \
    int p = (i << 9) + t; \
    float dx = rn_sub(sx[p], cx); \
    float dy = rn_sub(sy[p], cy); \
    float dz = rn_sub(szz[p], cz); \
    float s_ = rn_add(rn_add(rn_mul(dx,dx), rn_mul(dy,dy)), rn_mul(dz,dz)); \
    float d_ = fminf(dd##i, s_); \
    dd##i = d_; \
    unsigned long long k_ = ((unsigned long long)fkey(d_) << 32) \
                          | tag | (unsigned)(32767 - (base + p)); \
    if (k_ > bk) bk = k_; }
    REP8(DD_UPD)
#undef DD_UPD

    #pragma unroll
    for (int off = 32; off >= 1; off >>= 1){
      unsigned long long o = (unsigned long long)__shfl_xor((long long)bk, off);
      if (o > bk) bk = o;
    }
    if (ln == 0) skey[wv] = bk;
    __syncthreads();
    if (wv == 0){
      unsigned long long m = (ln < 8) ? skey[ln] : 0ull;
      #pragma unroll
      for (int off = 1; off <= 4; off <<= 1){
        unsigned long long o = (unsigned long long)__shfl_xor((long long)m, off);
        if (o > m) m = o;
      }
      if (ln == 0){
        int pl = (32767 - (int)(m & 0x7FFFu)) - base;   // own-slice local idx
        unsigned long long xy = ((unsigned long long)__float_as_uint(sx[pl]) << 32)
                              | (unsigned long long)__float_as_uint(sy[pl]);
        unsigned long long zz = (unsigned long long)__float_as_uint(szz[pl]);
        unsigned long long* S = &g_slot[((((b << 3) + sub) << 1) + (it & 1)) << 4];
        __hip_atomic_store(S + 1, xy, __ATOMIC_RELAXED, __HIP_MEMORY_SCOPE_AGENT);
        __hip_atomic_store(S + 2, zz, __ATOMIC_RELAXED, __HIP_MEMORY_SCOPE_AGENT);
        __hip_atomic_store(S + 0, m,  __ATOMIC_RELEASE, __HIP_MEMORY_SCOPE_AGENT);
      }
      unsigned long long k = 0ull, xy = 0ull, zz = 0ull;
      if (ln < 8){
        unsigned long long* S = &g_slot[((((b << 3) + ln) << 1) + (it & 1)) << 4];
        do {
          k = __hip_atomic_load(S + 0, __ATOMIC_ACQUIRE, __HIP_MEMORY_SCOPE_AGENT);
        } while ((((unsigned)k) >> 15) != (unsigned)(it + 1));
        xy = __hip_atomic_load(S + 1, __ATOMIC_RELAXED, __HIP_MEMORY_SCOPE_AGENT);
        zz = __hip_atomic_load(S + 2, __ATOMIC_RELAXED, __HIP_MEMORY_SCOPE_AGENT);
      }
      #pragma unroll
      for (int off = 1; off <= 4; off <<= 1){
        unsigned long long ok  = (unsigned long long)__shfl_xor((long long)k,  off);
        unsigned long long oxy = (unsigned long long)__shfl_xor((long long)xy, off);
        unsigned long long ozz = (unsigned long long)__shfl_xor((long long)zz, off);
        if (ok > k){ k = ok; xy = oxy; zz = ozz; }
      }
      if (ln == 0){
        s_far = 32767 - (int)(k & 0x7FFFu);
        s_cx = __uint_as_float((unsigned)(xy >> 32));
        s_cy = __uint_as_float((unsigned)(xy & 0xFFFFFFFFu));
        s_cz = __uint_as_float((unsigned)(zz & 0xFFFFFFFFu));
      }
    }
    __syncthreads();
    far = s_far; cx = s_cx; cy = s_cy; cz = s_cz;
    (void)far;
  }
}

// ---------------------------------------------------------------------------
// KNN v4 (validated r11/r12): 256 threads, float4 + precomputed n2,
// sort-based T, 1 block per (b,g).
// ---------------------------------------------------------------------------
__global__ __launch_bounds__(256) void k_knn(void){
  const int bg = blockIdx.x;
  const int b  = bg >> 6;
  const int t  = threadIdx.x;
  const int w  = t >> 6;
  const int ln = t & 63;
  const float4* X4 = (const float4*)(g_X  + (size_t)b*NN);
  const float4* Y4 = (const float4*)(g_Y  + (size_t)b*NN);
  const float4* Z4 = (const float4*)(g_Z  + (size_t)b*NN);
  const float4* N4 = (const float4*)(g_N2 + (size_t)b*NN);

  __shared__ unsigned sE[64];
  __shared__ unsigned long long s_cand[512];
  __shared__ int s_cnt;

  const float* cp = g_center + (size_t)bg*3;
  float cx = cp[0], cy = cp[1], cz = cp[2];
  float cn2 = rn_add(rn_add(rn_mul(cx,cx), rn_mul(cy,cy)), rn_mul(cz,cz));

  float e0 = INFINITY, e1 = INFINITY;
  #pragma unroll 2
  for (int s = 0; s < 32; ++s){
    int q = (s << 8) + t;
    float4 x = X4[q], y = Y4[q], z = Z4[q], n = N4[q];
    #define D2C(c) { \
      float e = rn_add(rn_add(rn_mul(cx,x.c), rn_mul(cy,y.c)), rn_mul(cz,z.c)); \
      float d = rn_sub(rn_add(cn2, n.c), rn_add(e,e)); \
      if (d < e1){ if (d < e0){ e1 = e0; e0 = d; } else e1 = d; } }
    D2C(x) D2C(y) D2C(z) D2C(w)
    #undef D2C
  }

  {
    unsigned v = fkey(e1);
    #pragma unroll
    for (int k = 2; k <= 64; k <<= 1){
      #pragma unroll
      for (int j = k >> 1; j > 0; j >>= 1){
        unsigned o = (unsigned)__shfl_xor((int)v, j);
        bool keepmin = (((ln & k) == 0) == ((ln & j) == 0));
        unsigned mn = o < v ? o : v;
        unsigned mx = o < v ? v : o;
        v = keepmin ? mn : mx;
      }
    }
    if (ln < 16) sE[w*16 + ln] = v;
  }
  if (t == 0) s_cnt = 0;
  __syncthreads();

  unsigned T;
  {
    unsigned v = sE[ln];
    #pragma unroll
    for (int k = 2; k <= 64; k <<= 1){
      #pragma unroll
      for (int j = k >> 1; j > 0; j >>= 1){
        unsigned o = (unsigned)__shfl_xor((int)v, j);
        bool keepmin = (((ln & k) == 0) == ((ln & j) == 0));
        unsigned mn = o < v ? o : v;
        unsigned mx = o < v ? v : o;
        v = keepmin ? mn : mx;
      }
    }
    T = (unsigned)__shfl((int)v, 15);
  }

  #pragma unroll 2
  for (int s = 0; s < 32; ++s){
    int q = (s << 8) + t;
    float4 x = X4[q], y = Y4[q], z = Z4[q], n = N4[q];
    #define COLC(c, kk) { \
      float e = rn_add(rn_add(rn_mul(cx,x.c), rn_mul(cy,y.c)), rn_mul(cz,z.c)); \
      float d = rn_sub(rn_add(cn2, n.c), rn_add(e,e)); \
      unsigned fk = fkey(d); \
      if (fk <= T){ \
        int p = atomicAdd(&s_cnt, 1); \
        if (p < 512) \
          s_cand[p] = ((unsigned long long)fk << 32) | (unsigned)((q<<2)+kk); } }
    COLC(x,0) COLC(y,1) COLC(z,2) COLC(w,3)
    #undef COLC
  }
  __syncthreads();

  if (w == 0){
    int C = s_cnt; if (C > 512) C = 512;
    int* kout = g_knn + (size_t)bg*KK;
    if (C <= 64){
      unsigned long long kk = (ln < C) ? s_cand[ln] : ~0ull;
      #pragma unroll
      for (int k = 2; k <= 64; k <<= 1){
        #pragma unroll
        for (int j = k >> 1; j > 0; j >>= 1){
          unsigned long long o = (unsigned long long)__shfl_xor((long long)kk, j);
          bool keepmin = (((ln & k) == 0) == ((ln & j) == 0));
          unsigned long long mn = o < kk ? o : kk;
          unsigned long long mx = o < kk ? kk : o;
          kk = keepmin ? mn : mx;
        }
      }
      if (ln < KK) kout[ln] = (int)(kk & 0xffffffffu);
    } else {
      unsigned long long md[8];
      #pragma unroll
      for (int j = 0; j < 8; ++j){
        int e = ln + (j << 6);
        md[j] = (e < C) ? s_cand[e] : ~0ull;
      }
      for (int r = 0; r < KK; ++r){
        unsigned long long bk = md[0];
        #pragma unroll
        for (int j = 1; j < 8; ++j) if (md[j] < bk) bk = md[j];
        #pragma unroll
        for (int off = 32; off >= 1; off >>= 1){
          unsigned long long o = (unsigned long long)__shfl_xor((long long)bk, off);
          if (o < bk) bk = o;
        }
        #pragma unroll
        for (int j = 0; j < 8; ++j) if (md[j] == bk) md[j] = ~0ull;
        if (ln == 0) kout[r] = (int)(bk & 0xffffffffu);
      }
    }
  }
}

// ---------------------------------------------------------------------------
// MLP v2 (validated r12): L1 VALU; L2/L3 mfma_f32_16x16x32_bf16.
// ---------------------------------------------------------------------------
__global__ __launch_bounds__(256) void k_mlp(const float* __restrict__ xyz,
                                             const float* __restrict__ feat,
                                             float* __restrict__ outPatch){
  const int bg = blockIdx.x;
  const int b  = bg >> 6;
  const int t  = threadIdx.x;
  const int w  = t >> 6;
  const int ln = t & 63;
  const float* xb = xyz  + (size_t)b*NN*3;
  const float* fb = feat + (size_t)b*NN*3;

  __shared__ float h0[KK][8];
  __shared__ __align__(16) unsigned short h1b[KK][72];
  __shared__ __align__(16) unsigned short h2b[KK][136];

  if (t < KK){
    int idx = g_knn[(size_t)bg*KK + t] & (NN - 1);
    const float* cp = g_center + (size_t)bg*3;
    h0[t][0] = rn_sub(xb[idx*3+0], cp[0]);
    h0[t][1] = rn_sub(xb[idx*3+1], cp[1]);
    h0[t][2] = rn_sub(xb[idx*3+2], cp[2]);
    h0[t][3] = fb[idx*3+0];
    h0[t][4] = fb[idx*3+1];
    h0[t][5] = fb[idx*3+2];
  }
  __syncthreads();

  {
    int p = t >> 3, ob = (t & 7) * 8;
    float acc[8];
    #pragma unroll
    for (int j = 0; j < 8; ++j) acc[j] = g_b1[ob + j];
    #pragma unroll
    for (int c = 0; c < 6; ++c){
      float a = h0[p][c];
      const float4* wr = (const float4*)(g_w1t + c*64 + ob);
      float4 wa = wr[0], wb = wr[1];
      acc[0] = fmaf(a, wa.x, acc[0]); acc[1] = fmaf(a, wa.y, acc[1]);
      acc[2] = fmaf(a, wa.z, acc[2]); acc[3] = fmaf(a, wa.w, acc[3]);
      acc[4] = fmaf(a, wb.x, acc[4]); acc[5] = fmaf(a, wb.y, acc[5]);
      acc[6] = fmaf(a, wb.z, acc[6]); acc[7] = fmaf(a, wb.w, acc[7]);
    }
    short8 v;
    #pragma unroll
    for (int j = 0; j < 8; ++j) v[j] = (short)f2bf(fmaxf(acc[j], 0.f));
    *reinterpret_cast<short8*>(&h1b[p][ob]) = v;
  }
  __syncthreads();

  {
    f32x4 a00 = {0,0,0,0}, a01 = {0,0,0,0}, a10 = {0,0,0,0}, a11 = {0,0,0,0};
    const int g8 = (ln >> 4) << 3;
    #pragma unroll
    for (int kk = 0; kk < 2; ++kk){
      short8 A0 = *reinterpret_cast<const short8*>(&h1b[(ln & 15)][kk*32 + g8]);
      short8 A1 = *reinterpret_cast<const short8*>(&h1b[16 + (ln & 15)][kk*32 + g8]);
      short8 B0 = *reinterpret_cast<const short8*>(&g_w2f[(((2*w+0)*2 + kk)*64 + ln)*8]);
      short8 B1 = *reinterpret_cast<const short8*>(&g_w2f[(((2*w+1)*2 + kk)*64 + ln)*8]);
      a00 = __builtin_amdgcn_mfma_f32_16x16x32_bf16(A0, B0, a00, 0, 0, 0);
      a01 = __builtin_amdgcn_mfma_f32_16x16x32_bf16(A1, B0, a01, 0, 0, 0);
      a10 = __builtin_amdgcn_mfma_f32_16x16x32_bf16(A0, B1, a10, 0, 0, 0);
      a11 = __builtin_amdgcn_mfma_f32_16x16x32_bf16(A1, B1, a11, 0, 0, 0);
    }
    int col0 = (2*w)*16 + (ln & 15);
    int col1 = col0 + 16;
    float bz0 = g_b2[col0], bz1 = g_b2[col1];
    int r0 = (ln >> 4) << 2;
    #pragma unroll
    for (int r = 0; r < 4; ++r){
      h2b[r0 + r][col0]      = f2bf(fmaxf(a00[r] + bz0, 0.f));
      h2b[16 + r0 + r][col0] = f2bf(fmaxf(a01[r] + bz0, 0.f));
      h2b[r0 + r][col1]      = f2bf(fmaxf(a10[r] + bz1, 0.f));
      h2b[16 + r0 + r][col1] = f2bf(fmaxf(a11[r] + bz1, 0.f));
    }
  }
  __syncthreads();

  {
    f32x4 acc3[6][2];
    #pragma unroll
    for (int ci = 0; ci < 6; ++ci){
      acc3[ci][0] = (f32x4){0,0,0,0};
      acc3[ci][1] = (f32x4){0,0,0,0};
    }
    const int g8 = (ln >> 4) << 3;
    #pragma unroll
    for (int kk = 0; kk < 4; ++kk){
      short8 A0 = *reinterpret_cast<const short8*>(&h2b[(ln & 15)][kk*32 + g8]);
      short8 A1 = *reinterpret_cast<const short8*>(&h2b[16 + (ln & 15)][kk*32 + g8]);
      #pragma unroll
      for (int ci = 0; ci < 6; ++ci){
        int ct = w*6 + ci;
        short8 B = *reinterpret_cast<const short8*>(&g_w3f[((ct*4 + kk)*64 + ln)*8]);
        acc3[ci][0] = __builtin_amdgcn_mfma_f32_16x16x32_bf16(A0, B, acc3[ci][0], 0, 0, 0);
        acc3[ci][1] = __builtin_amdgcn_mfma_f32_16x16x32_bf16(A1, B, acc3[ci][1], 0, 0, 0);
      }
    }
    #pragma unroll
    for (int ci = 0; ci < 6; ++ci){
      float m = acc3[ci][0][0];
      #pragma unroll
      for (int r = 1; r < 4; ++r) m = fmaxf(m, acc3[ci][0][r]);
      #pragma unroll
      for (int r = 0; r < 4; ++r) m = fmaxf(m, acc3[ci][1][r]);
      m = fmaxf(m, __shfl_xor(m, 16));
      m = fmaxf(m, __shfl_xor(m, 32));
      if (ln < 16){
        int col = (w*6 + ci)*16 + ln;
        outPatch[(size_t)bg*DD + col] = m + g_b3[col];
      }
    }
  }
}

// ---------------------------------------------------------------------------
extern "C" void kernel_launch(void* const* d_in, const int* in_sizes, int n_in,
                              void* d_out, int out_size, void* d_ws, size_t ws_size,
                              hipStream_t stream){
  (void)in_sizes; (void)n_in; (void)out_size; (void)d_ws; (void)ws_size;
  const float* xyz  = (const float*)d_in[0];
  const float* feat = (const float*)d_in[1];
  const float* w1 = (const float*)d_in[2];
  const float* g1 = (const float*)d_in[3];
  const float* b1 = (const float*)d_in[4];
  const float* m1 = (const float*)d_in[5];
  const float* v1 = (const float*)d_in[6];
  const float* w2 = (const float*)d_in[7];
  const float* g2 = (const float*)d_in[8];
  const float* b2 = (const float*)d_in[9];
  const float* m2 = (const float*)d_in[10];
  const float* v2 = (const float*)d_in[11];
  const float* w3 = (const float*)d_in[12];
  const float* g3 = (const float*)d_in[13];
  const float* b3 = (const float*)d_in[14];
  const float* m3 = (const float*)d_in[15];
  const float* v3 = (const float*)d_in[16];
  float* out = (float*)d_out;

  k_prep<<<64, 256, 0, stream>>>(w1,g1,b1,m1,v1, w2,g2,b2,m2,v2, w3,g3,b3,m3,v3);
  k_soa<<<(BB*NN)/256, 256, 0, stream>>>(xyz);
  k_zero<<<64, 256, 0, stream>>>();
  k_fps<<<BB*FPS_NBLK, 512, 0, stream>>>(out);
  k_knn<<<BB*GG, 256, 0, stream>>>();
  k_mlp<<<BB*GG, 256, 0, stream>>>(xyz, feat, out + (size_t)BB*GG*3);
}

// Round 16
// 267.270 us; speedup vs baseline: 2.0073x; 2.0073x over previous
//
#include <hip/hip_runtime.h>
#include <hip/hip_bf16.h>

#define BB 32
#define NN 32768
#define GG 64
#define KK 32
#define DD 384
#define EPSF 1e-5f
#define FPS_NBLK 8
#define FPS_SL   (NN/FPS_NBLK)

typedef __attribute__((ext_vector_type(8))) short short8;
typedef __attribute__((ext_vector_type(4))) float f32x4;

__device__ __forceinline__ float rn_add(float a, float b){ return __fadd_rn(a,b); }
__device__ __forceinline__ float rn_sub(float a, float b){ return __fsub_rn(a,b); }
__device__ __forceinline__ float rn_mul(float a, float b){ return __fmul_rn(a,b); }

__device__ __forceinline__ unsigned fkey(float d){
  unsigned u = __float_as_uint(d);
  return (u & 0x80000000u) ? ~u : (u | 0x80000000u);
}

__device__ __forceinline__ unsigned short f2bf(float f){
  unsigned u = __float_as_uint(f);
  unsigned r = (u + 0x7FFFu + ((u >> 16) & 1u)) >> 16;
  return (unsigned short)r;
}

#define REP8(X) X(0) X(1) X(2) X(3) X(4) X(5) X(6) X(7)

// ---- module-scope scratch ------------------------------------------------
__device__ float g_center[BB*GG*3];
__device__ int   g_knn[BB*GG*KK];
__device__ float g_w1t[6*64];
__device__ float g_b1[64];
__device__ float g_b2[128];
__device__ float g_b3[384];
__device__ __align__(16) unsigned short g_w2f[8*2*64*8];    // w2 MFMA frags
__device__ __align__(16) unsigned short g_w3f[24*4*64*8];   // w3 MFMA frags
__device__ float g_X[BB*NN];
__device__ float g_Y[BB*NN];
__device__ float g_Z[BB*NN];
__device__ float g_N2[BB*NN];
__device__ unsigned long long g_part[BB*FPS_NBLK*GG];

// ---------------------------------------------------------------------------
// One-shot AoS -> SoA repack + n2 precompute (bit-exact rn sequence).
// ---------------------------------------------------------------------------
__global__ __launch_bounds__(256) void k_soa(const float* __restrict__ xyz){
  int tid = blockIdx.x * blockDim.x + threadIdx.x;
  int b = tid >> 15;
  int p = tid & (NN - 1);
  const float* s = xyz + (size_t)b*NN*3 + (size_t)p*3;
  float x = s[0], y = s[1], z = s[2];
  g_X[tid] = x;
  g_Y[tid] = y;
  g_Z[tid] = z;
  g_N2[tid] = rn_add(rn_add(rn_mul(x,x), rn_mul(y,y)), rn_mul(z,z));
}

__global__ __launch_bounds__(256) void k_zero(void){
  int tid = blockIdx.x * blockDim.x + threadIdx.x;
  if (tid < BB*FPS_NBLK*GG) g_part[tid] = 0ull;
}

// ---------------------------------------------------------------------------
// Weight prep (validated r12): fold BN; w1 transposed f32; w2/w3 bf16 frags.
// ---------------------------------------------------------------------------
__global__ void k_prep(const float* __restrict__ w1, const float* __restrict__ g1, const float* __restrict__ b1, const float* __restrict__ m1, const float* __restrict__ v1,
                       const float* __restrict__ w2, const float* __restrict__ g2, const float* __restrict__ b2, const float* __restrict__ m2, const float* __restrict__ v2,
                       const float* __restrict__ w3, const float* __restrict__ g3, const float* __restrict__ b3, const float* __restrict__ m3, const float* __restrict__ v3){
  int tid = blockIdx.x * blockDim.x + threadIdx.x;
  int nt  = gridDim.x * blockDim.x;
  for (int e = tid; e < 64*6; e += nt){
    int c = e >> 6, o = e & 63;
    float s = g1[o] * rsqrtf(v1[o] + EPSF);
    g_w1t[e] = w1[o*6 + c] * s;
  }
  for (int o = tid; o < 64; o += nt){
    float s = g1[o] * rsqrtf(v1[o] + EPSF);
    g_b1[o] = b1[o] - m1[o]*s;
  }
  for (int o = tid; o < 128; o += nt){
    float s = g2[o] * rsqrtf(v2[o] + EPSF);
    g_b2[o] = b2[o] - m2[o]*s;
  }
  for (int o = tid; o < 384; o += nt){
    float s = g3[o] * rsqrtf(v3[o] + EPSF);
    g_b3[o] = b3[o] - m3[o]*s;
  }
  for (int idx = tid; idx < 8192; idx += nt){
    int e  = idx & 7;
    int l  = (idx >> 3) & 63;
    int kt = (idx >> 9) & 1;
    int ct = idx >> 10;
    int j  = ct*16 + (l & 15);
    int k  = kt*32 + ((l >> 4) << 3) + e;
    float s = g2[j] * rsqrtf(v2[j] + EPSF);
    g_w2f[idx] = f2bf(w2[j*64 + k] * s);
  }
  for (int idx = tid; idx < 49152; idx += nt){
    int e  = idx & 7;
    int l  = (idx >> 3) & 63;
    int kt = (idx >> 9) & 3;
    int ct = idx >> 11;
    int j  = ct*16 + (l & 15);
    int k  = kt*32 + ((l >> 4) << 3) + e;
    float s = g3[j] * rsqrtf(v3[j] + EPSF);
    g_w3f[idx] = f2bf(w3[j*128 + k] * s);
  }
}

// ---------------------------------------------------------------------------
// FPS v8 = r14-validated v6 exchange (relaxed store/poll, slot-per-iter,
// XCD co-location remap) with ONE isolated change: 512 threads (8 pts/thr).
// Rationale: at 256 thr the block is 1 wave/SIMD -> 48 dependent ds_reads
// (~120cy) in the compute phase are fully exposed; 2 waves/SIMD hides them.
// r15's 3x regression is attributed to ACQUIRE-in-spin (L1-invalidate per
// poll) -- NOT repeated here; relaxed scheme is self-validating (key != 0).
// ---------------------------------------------------------------------------
__global__ __launch_bounds__(512)
void k_fps(float* __restrict__ outCenter){
  const int blk = blockIdx.x;
  const int b   = blk & 31;          // batch (XCD co-location remap, r14)
  const int sub = blk >> 5;          // sub-block 0..7
  const int t   = threadIdx.x;
  const int wv  = t >> 6, ln = t & 63;
  const int base = sub * FPS_SL;
  const float* Xb = g_X + (size_t)b*NN;
  const float* Yb = g_Y + (size_t)b*NN;
  const float* Zb = g_Z + (size_t)b*NN;

  __shared__ float sx[FPS_SL], sy[FPS_SL], szz[FPS_SL];
  __shared__ unsigned long long skey[8];
  __shared__ int s_far;

  #pragma unroll
  for (int i = 0; i < 8; ++i){
    int p = (i << 9) + t;
    sx[p]  = Xb[base + p];
    sy[p]  = Yb[base + p];
    szz[p] = Zb[base + p];
  }
  __syncthreads();

#define DD_DECL(i) float dd##i = 1e10f;
  REP8(DD_DECL)
#undef DD_DECL

  int far = 0;
  for (int it = 0; ; ++it){
    if (sub == 0 && t == 0){
      float cx = Xb[far], cy = Yb[far], cz = Zb[far];
      float* cw = g_center  + (size_t)(b*GG + it)*3;
      float* co = outCenter + (size_t)(b*GG + it)*3;
      cw[0] = cx; cw[1] = cy; cw[2] = cz;
      co[0] = cx; co[1] = cy; co[2] = cz;
    }
    if (it == GG - 1) break;

    float cx = Xb[far], cy = Yb[far], cz = Zb[far];   // L2-resident reads
    unsigned long long bk = 0ull;
    // ascending i => ascending point idx; keys unique (idx embedded) so
    // max key == (max d, tie -> lowest idx) == numpy argmax.
#define DD_UPD(i) { \
    int p = (i << 9) + t; \
    float dx = rn_sub(sx[p], cx); \
    float dy = rn_sub(sy[p], cy); \
    float dz = rn_sub(szz[p], cz); \
    float s_ = rn_add(rn_add(rn_mul(dx,dx), rn_mul(dy,dy)), rn_mul(dz,dz)); \
    float d_ = fminf(dd##i, s_); \
    dd##i = d_; \
    unsigned long long k_ = ((unsigned long long)fkey(d_) << 32) \
                          | (unsigned)(0xFFFFFFFFu - (unsigned)(base + p)); \
    if (k_ > bk) bk = k_; }
    REP8(DD_UPD)
#undef DD_UPD

    #pragma unroll
    for (int off = 32; off >= 1; off >>= 1){
      unsigned long long o = (unsigned long long)__shfl_xor((long long)bk, off);
      if (o > bk) bk = o;
    }
    if (ln == 0) skey[wv] = bk;
    __syncthreads();
    if (wv == 0){
      unsigned long long m = (ln < 8) ? skey[ln] : 0ull;
      #pragma unroll
      for (int off = 1; off <= 4; off <<= 1){
        unsigned long long o = (unsigned long long)__shfl_xor((long long)m, off);
        if (o > m) m = o;
      }
      if (ln == 0)
        __hip_atomic_store(&g_part[(((b << 3) + sub) << 6) + it], m,
                           __ATOMIC_RELAXED, __HIP_MEMORY_SCOPE_AGENT);
      unsigned long long k = 0ull;
      if (ln < 8){
        unsigned long long* p = &g_part[(((b << 3) + ln) << 6) + it];
        do {
          k = __hip_atomic_load(p, __ATOMIC_RELAXED, __HIP_MEMORY_SCOPE_AGENT);
        } while (k == 0ull);
      }
      #pragma unroll
      for (int off = 1; off <= 4; off <<= 1){
        unsigned long long o = (unsigned long long)__shfl_xor((long long)k, off);
        if (o > k) k = o;
      }
      if (ln == 0) s_far = (int)(0xFFFFFFFFu - (unsigned)(k & 0xFFFFFFFFu));
    }
    __syncthreads();
    far = s_far;
  }
}

// ---------------------------------------------------------------------------
// KNN v4 (validated r11/r12): 256 threads, float4 + precomputed n2,
// sort-based T, 1 block per (b,g).
// ---------------------------------------------------------------------------
__global__ __launch_bounds__(256) void k_knn(void){
  const int bg = blockIdx.x;
  const int b  = bg >> 6;
  const int t  = threadIdx.x;
  const int w  = t >> 6;
  const int ln = t & 63;
  const float4* X4 = (const float4*)(g_X  + (size_t)b*NN);
  const float4* Y4 = (const float4*)(g_Y  + (size_t)b*NN);
  const float4* Z4 = (const float4*)(g_Z  + (size_t)b*NN);
  const float4* N4 = (const float4*)(g_N2 + (size_t)b*NN);

  __shared__ unsigned sE[64];
  __shared__ unsigned long long s_cand[512];
  __shared__ int s_cnt;

  const float* cp = g_center + (size_t)bg*3;
  float cx = cp[0], cy = cp[1], cz = cp[2];
  float cn2 = rn_add(rn_add(rn_mul(cx,cx), rn_mul(cy,cy)), rn_mul(cz,cz));

  float e0 = INFINITY, e1 = INFINITY;
  #pragma unroll 2
  for (int s = 0; s < 32; ++s){
    int q = (s << 8) + t;
    float4 x = X4[q], y = Y4[q], z = Z4[q], n = N4[q];
    #define D2C(c) { \
      float e = rn_add(rn_add(rn_mul(cx,x.c), rn_mul(cy,y.c)), rn_mul(cz,z.c)); \
      float d = rn_sub(rn_add(cn2, n.c), rn_add(e,e)); \
      if (d < e1){ if (d < e0){ e1 = e0; e0 = d; } else e1 = d; } }
    D2C(x) D2C(y) D2C(z) D2C(w)
    #undef D2C
  }

  {
    unsigned v = fkey(e1);
    #pragma unroll
    for (int k = 2; k <= 64; k <<= 1){
      #pragma unroll
      for (int j = k >> 1; j > 0; j >>= 1){
        unsigned o = (unsigned)__shfl_xor((int)v, j);
        bool keepmin = (((ln & k) == 0) == ((ln & j) == 0));
        unsigned mn = o < v ? o : v;
        unsigned mx = o < v ? v : o;
        v = keepmin ? mn : mx;
      }
    }
    if (ln < 16) sE[w*16 + ln] = v;
  }
  if (t == 0) s_cnt = 0;
  __syncthreads();

  unsigned T;
  {
    unsigned v = sE[ln];
    #pragma unroll
    for (int k = 2; k <= 64; k <<= 1){
      #pragma unroll
      for (int j = k >> 1; j > 0; j >>= 1){
        unsigned o = (unsigned)__shfl_xor((int)v, j);
        bool keepmin = (((ln & k) == 0) == ((ln & j) == 0));
        unsigned mn = o < v ? o : v;
        unsigned mx = o < v ? v : o;
        v = keepmin ? mn : mx;
      }
    }
    T = (unsigned)__shfl((int)v, 15);
  }

  #pragma unroll 2
  for (int s = 0; s < 32; ++s){
    int q = (s << 8) + t;
    float4 x = X4[q], y = Y4[q], z = Z4[q], n = N4[q];
    #define COLC(c, kk) { \
      float e = rn_add(rn_add(rn_mul(cx,x.c), rn_mul(cy,y.c)), rn_mul(cz,z.c)); \
      float d = rn_sub(rn_add(cn2, n.c), rn_add(e,e)); \
      unsigned fk = fkey(d); \
      if (fk <= T){ \
        int p = atomicAdd(&s_cnt, 1); \
        if (p < 512) \
          s_cand[p] = ((unsigned long long)fk << 32) | (unsigned)((q<<2)+kk); } }
    COLC(x,0) COLC(y,1) COLC(z,2) COLC(w,3)
    #undef COLC
  }
  __syncthreads();

  if (w == 0){
    int C = s_cnt; if (C > 512) C = 512;
    int* kout = g_knn + (size_t)bg*KK;
    if (C <= 64){
      unsigned long long kk = (ln < C) ? s_cand[ln] : ~0ull;
      #pragma unroll
      for (int k = 2; k <= 64; k <<= 1){
        #pragma unroll
        for (int j = k >> 1; j > 0; j >>= 1){
          unsigned long long o = (unsigned long long)__shfl_xor((long long)kk, j);
          bool keepmin = (((ln & k) == 0) == ((ln & j) == 0));
          unsigned long long mn = o < kk ? o : kk;
          unsigned long long mx = o < kk ? kk : o;
          kk = keepmin ? mn : mx;
        }
      }
      if (ln < KK) kout[ln] = (int)(kk & 0xffffffffu);
    } else {
      unsigned long long md[8];
      #pragma unroll
      for (int j = 0; j < 8; ++j){
        int e = ln + (j << 6);
        md[j] = (e < C) ? s_cand[e] : ~0ull;
      }
      for (int r = 0; r < KK; ++r){
        unsigned long long bk = md[0];
        #pragma unroll
        for (int j = 1; j < 8; ++j) if (md[j] < bk) bk = md[j];
        #pragma unroll
        for (int off = 32; off >= 1; off >>= 1){
          unsigned long long o = (unsigned long long)__shfl_xor((long long)bk, off);
          if (o < bk) bk = o;
        }
        #pragma unroll
        for (int j = 0; j < 8; ++j) if (md[j] == bk) md[j] = ~0ull;
        if (ln == 0) kout[r] = (int)(bk & 0xffffffffu);
      }
    }
  }
}

// ---------------------------------------------------------------------------
// MLP v2 (validated r12): L1 VALU; L2/L3 mfma_f32_16x16x32_bf16.
// ---------------------------------------------------------------------------
__global__ __launch_bounds__(256) void k_mlp(const float* __restrict__ xyz,
                                             const float* __restrict__ feat,
                                             float* __restrict__ outPatch){
  const int bg = blockIdx.x;
  const int b  = bg >> 6;
  const int t  = threadIdx.x;
  const int w  = t >> 6;
  const int ln = t & 63;
  const float* xb = xyz  + (size_t)b*NN*3;
  const float* fb = feat + (size_t)b*NN*3;

  __shared__ float h0[KK][8];
  __shared__ __align__(16) unsigned short h1b[KK][72];
  __shared__ __align__(16) unsigned short h2b[KK][136];

  if (t < KK){
    int idx = g_knn[(size_t)bg*KK + t] & (NN - 1);
    const float* cp = g_center + (size_t)bg*3;
    h0[t][0] = rn_sub(xb[idx*3+0], cp[0]);
    h0[t][1] = rn_sub(xb[idx*3+1], cp[1]);
    h0[t][2] = rn_sub(xb[idx*3+2], cp[2]);
    h0[t][3] = fb[idx*3+0];
    h0[t][4] = fb[idx*3+1];
    h0[t][5] = fb[idx*3+2];
  }
  __syncthreads();

  {
    int p = t >> 3, ob = (t & 7) * 8;
    float acc[8];
    #pragma unroll
    for (int j = 0; j < 8; ++j) acc[j] = g_b1[ob + j];
    #pragma unroll
    for (int c = 0; c < 6; ++c){
      float a = h0[p][c];
      const float4* wr = (const float4*)(g_w1t + c*64 + ob);
      float4 wa = wr[0], wb = wr[1];
      acc[0] = fmaf(a, wa.x, acc[0]); acc[1] = fmaf(a, wa.y, acc[1]);
      acc[2] = fmaf(a, wa.z, acc[2]); acc[3] = fmaf(a, wa.w, acc[3]);
      acc[4] = fmaf(a, wb.x, acc[4]); acc[5] = fmaf(a, wb.y, acc[5]);
      acc[6] = fmaf(a, wb.z, acc[6]); acc[7] = fmaf(a, wb.w, acc[7]);
    }
    short8 v;
    #pragma unroll
    for (int j = 0; j < 8; ++j) v[j] = (short)f2bf(fmaxf(acc[j], 0.f));
    *reinterpret_cast<short8*>(&h1b[p][ob]) = v;
  }
  __syncthreads();

  {
    f32x4 a00 = {0,0,0,0}, a01 = {0,0,0,0}, a10 = {0,0,0,0}, a11 = {0,0,0,0};
    const int g8 = (ln >> 4) << 3;
    #pragma unroll
    for (int kk = 0; kk < 2; ++kk){
      short8 A0 = *reinterpret_cast<const short8*>(&h1b[(ln & 15)][kk*32 + g8]);
      short8 A1 = *reinterpret_cast<const short8*>(&h1b[16 + (ln & 15)][kk*32 + g8]);
      short8 B0 = *reinterpret_cast<const short8*>(&g_w2f[(((2*w+0)*2 + kk)*64 + ln)*8]);
      short8 B1 = *reinterpret_cast<const short8*>(&g_w2f[(((2*w+1)*2 + kk)*64 + ln)*8]);
      a00 = __builtin_amdgcn_mfma_f32_16x16x32_bf16(A0, B0, a00, 0, 0, 0);
      a01 = __builtin_amdgcn_mfma_f32_16x16x32_bf16(A1, B0, a01, 0, 0, 0);
      a10 = __builtin_amdgcn_mfma_f32_16x16x32_bf16(A0, B1, a10, 0, 0, 0);
      a11 = __builtin_amdgcn_mfma_f32_16x16x32_bf16(A1, B1, a11, 0, 0, 0);
    }
    int col0 = (2*w)*16 + (ln & 15);
    int col1 = col0 + 16;
    float bz0 = g_b2[col0], bz1 = g_b2[col1];
    int r0 = (ln >> 4) << 2;
    #pragma unroll
    for (int r = 0; r < 4; ++r){
      h2b[r0 + r][col0]      = f2bf(fmaxf(a00[r] + bz0, 0.f));
      h2b[16 + r0 + r][col0] = f2bf(fmaxf(a01[r] + bz0, 0.f));
      h2b[r0 + r][col1]      = f2bf(fmaxf(a10[r] + bz1, 0.f));
      h2b[16 + r0 + r][col1] = f2bf(fmaxf(a11[r] + bz1, 0.f));
    }
  }
  __syncthreads();

  {
    f32x4 acc3[6][2];
    #pragma unroll
    for (int ci = 0; ci < 6; ++ci){
      acc3[ci][0] = (f32x4){0,0,0,0};
      acc3[ci][1] = (f32x4){0,0,0,0};
    }
    const int g8 = (ln >> 4) << 3;
    #pragma unroll
    for (int kk = 0; kk < 4; ++kk){
      short8 A0 = *reinterpret_cast<const short8*>(&h2b[(ln & 15)][kk*32 + g8]);
      short8 A1 = *reinterpret_cast<const short8*>(&h2b[16 + (ln & 15)][kk*32 + g8]);
      #pragma unroll
      for (int ci = 0; ci < 6; ++ci){
        int ct = w*6 + ci;
        short8 B = *reinterpret_cast<const short8*>(&g_w3f[((ct*4 + kk)*64 + ln)*8]);
        acc3[ci][0] = __builtin_amdgcn_mfma_f32_16x16x32_bf16(A0, B, acc3[ci][0], 0, 0, 0);
        acc3[ci][1] = __builtin_amdgcn_mfma_f32_16x16x32_bf16(A1, B, acc3[ci][1], 0, 0, 0);
      }
    }
    #pragma unroll
    for (int ci = 0; ci < 6; ++ci){
      float m = acc3[ci][0][0];
      #pragma unroll
      for (int r = 1; r < 4; ++r) m = fmaxf(m, acc3[ci][0][r]);
      #pragma unroll
      for (int r = 0; r < 4; ++r) m = fmaxf(m, acc3[ci][1][r]);
      m = fmaxf(m, __shfl_xor(m, 16));
      m = fmaxf(m, __shfl_xor(m, 32));
      if (ln < 16){
        int col = (w*6 + ci)*16 + ln;
        outPatch[(size_t)bg*DD + col] = m + g_b3[col];
      }
    }
  }
}

// ---------------------------------------------------------------------------
extern "C" void kernel_launch(void* const* d_in, const int* in_sizes, int n_in,
                              void* d_out, int out_size, void* d_ws, size_t ws_size,
                              hipStream_t stream){
  (void)in_sizes; (void)n_in; (void)out_size; (void)d_ws; (void)ws_size;
  const float* xyz  = (const float*)d_in[0];
  const float* feat = (const float*)d_in[1];
  const float* w1 = (const float*)d_in[2];
  const float* g1 = (const float*)d_in[3];
  const float* b1 = (const float*)d_in[4];
  const float* m1 = (const float*)d_in[5];
  const float* v1 = (const float*)d_in[6];
  const float* w2 = (const float*)d_in[7];
  const float* g2 = (const float*)d_in[8];
  const float* b2 = (const float*)d_in[9];
  const float* m2 = (const float*)d_in[10];
  const float* v2 = (const float*)d_in[11];
  const float* w3 = (const float*)d_in[12];
  const float* g3 = (const float*)d_in[13];
  const float* b3 = (const float*)d_in[14];
  const float* m3 = (const float*)d_in[15];
  const float* v3 = (const float*)d_in[16];
  float* out = (float*)d_out;

  k_prep<<<64, 256, 0, stream>>>(w1,g1,b1,m1,v1, w2,g2,b2,m2,v2, w3,g3,b3,m3,v3);
  k_soa<<<(BB*NN)/256, 256, 0, stream>>>(xyz);
  k_zero<<<64, 256, 0, stream>>>();
  k_fps<<<BB*FPS_NBLK, 512, 0, stream>>>(out);
  k_knn<<<BB*GG, 256, 0, stream>>>();
  k_mlp<<<BB*GG, 256, 0, stream>>>(xyz, feat, out + (size_t)BB*GG*3);
}

// Round 17
// 245.859 us; speedup vs baseline: 2.1821x; 1.0871x over previous
//
#include <hip/hip_runtime.h>
#include <hip/hip_bf16.h>

#define BB 32
#define NN 32768
#define GG 64
#define KK 32
#define DD 384
#define EPSF 1e-5f
#define FPS_NBLK 8
#define FPS_SL   (NN/FPS_NBLK)

typedef __attribute__((ext_vector_type(8))) short short8;
typedef __attribute__((ext_vector_type(4))) float f32x4;

__device__ __forceinline__ float rn_add(float a, float b){ return __fadd_rn(a,b); }
__device__ __forceinline__ float rn_sub(float a, float b){ return __fsub_rn(a,b); }
__device__ __forceinline__ float rn_mul(float a, float b){ return __fmul_rn(a,b); }

__device__ __forceinline__ unsigned fkey(float d){
  unsigned u = __float_as_uint(d);
  return (u & 0x80000000u) ? ~u : (u | 0x80000000u);
}

__device__ __forceinline__ unsigned short f2bf(float f){
  unsigned u = __float_as_uint(f);
  unsigned r = (u + 0x7FFFu + ((u >> 16) & 1u)) >> 16;
  return (unsigned short)r;
}

#define REP8(X) X(0) X(1) X(2) X(3) X(4) X(5) X(6) X(7)

// ---- module-scope scratch ------------------------------------------------
__device__ float g_center[BB*GG*3];
__device__ int   g_knn[BB*GG*KK];
__device__ float g_w1t[6*64];
__device__ float g_b1[64];
__device__ float g_b2[128];
__device__ float g_b3[384];
__device__ __align__(16) unsigned short g_w2f[8*2*64*8];    // w2 MFMA frags
__device__ __align__(16) unsigned short g_w3f[24*4*64*8];   // w3 MFMA frags
__device__ float g_X[BB*NN];
__device__ float g_Y[BB*NN];
__device__ float g_Z[BB*NN];
__device__ float g_N2[BB*NN];
__device__ unsigned long long g_part[BB*FPS_NBLK*GG];

// ---------------------------------------------------------------------------
// One-shot AoS -> SoA repack + n2 precompute (bit-exact rn sequence).
// ---------------------------------------------------------------------------
__global__ __launch_bounds__(256) void k_soa(const float* __restrict__ xyz){
  int tid = blockIdx.x * blockDim.x + threadIdx.x;
  int b = tid >> 15;
  int p = tid & (NN - 1);
  const float* s = xyz + (size_t)b*NN*3 + (size_t)p*3;
  float x = s[0], y = s[1], z = s[2];
  g_X[tid] = x;
  g_Y[tid] = y;
  g_Z[tid] = z;
  g_N2[tid] = rn_add(rn_add(rn_mul(x,x), rn_mul(y,y)), rn_mul(z,z));
}

__global__ __launch_bounds__(256) void k_zero(void){
  int tid = blockIdx.x * blockDim.x + threadIdx.x;
  if (tid < BB*FPS_NBLK*GG) g_part[tid] = 0ull;
}

// ---------------------------------------------------------------------------
// Weight prep (validated r12): fold BN; w1 transposed f32; w2/w3 bf16 frags.
// ---------------------------------------------------------------------------
__global__ void k_prep(const float* __restrict__ w1, const float* __restrict__ g1, const float* __restrict__ b1, const float* __restrict__ m1, const float* __restrict__ v1,
                       const float* __restrict__ w2, const float* __restrict__ g2, const float* __restrict__ b2, const float* __restrict__ m2, const float* __restrict__ v2,
                       const float* __restrict__ w3, const float* __restrict__ g3, const float* __restrict__ b3, const float* __restrict__ m3, const float* __restrict__ v3){
  int tid = blockIdx.x * blockDim.x + threadIdx.x;
  int nt  = gridDim.x * blockDim.x;
  for (int e = tid; e < 64*6; e += nt){
    int c = e >> 6, o = e & 63;
    float s = g1[o] * rsqrtf(v1[o] + EPSF);
    g_w1t[e] = w1[o*6 + c] * s;
  }
  for (int o = tid; o < 64; o += nt){
    float s = g1[o] * rsqrtf(v1[o] + EPSF);
    g_b1[o] = b1[o] - m1[o]*s;
  }
  for (int o = tid; o < 128; o += nt){
    float s = g2[o] * rsqrtf(v2[o] + EPSF);
    g_b2[o] = b2[o] - m2[o]*s;
  }
  for (int o = tid; o < 384; o += nt){
    float s = g3[o] * rsqrtf(v3[o] + EPSF);
    g_b3[o] = b3[o] - m3[o]*s;
  }
  for (int idx = tid; idx < 8192; idx += nt){
    int e  = idx & 7;
    int l  = (idx >> 3) & 63;
    int kt = (idx >> 9) & 1;
    int ct = idx >> 10;
    int j  = ct*16 + (l & 15);
    int k  = kt*32 + ((l >> 4) << 3) + e;
    float s = g2[j] * rsqrtf(v2[j] + EPSF);
    g_w2f[idx] = f2bf(w2[j*64 + k] * s);
  }
  for (int idx = tid; idx < 49152; idx += nt){
    int e  = idx & 7;
    int l  = (idx >> 3) & 63;
    int kt = (idx >> 9) & 3;
    int ct = idx >> 11;
    int j  = ct*16 + (l & 15);
    int k  = kt*32 + ((l >> 4) << 3) + e;
    float s = g3[j] * rsqrtf(v3[j] + EPSF);
    g_w3f[idx] = f2bf(w3[j*128 + k] * s);
  }
}

// ---------------------------------------------------------------------------
// FPS v8 (validated r16): 512 threads, relaxed store/poll exchange,
// XCD co-location remap. ~1.97us/iter.
// ---------------------------------------------------------------------------
__global__ __launch_bounds__(512)
void k_fps(float* __restrict__ outCenter){
  const int blk = blockIdx.x;
  const int b   = blk & 31;
  const int sub = blk >> 5;
  const int t   = threadIdx.x;
  const int wv  = t >> 6, ln = t & 63;
  const int base = sub * FPS_SL;
  const float* Xb = g_X + (size_t)b*NN;
  const float* Yb = g_Y + (size_t)b*NN;
  const float* Zb = g_Z + (size_t)b*NN;

  __shared__ float sx[FPS_SL], sy[FPS_SL], szz[FPS_SL];
  __shared__ unsigned long long skey[8];
  __shared__ int s_far;

  #pragma unroll
  for (int i = 0; i < 8; ++i){
    int p = (i << 9) + t;
    sx[p]  = Xb[base + p];
    sy[p]  = Yb[base + p];
    szz[p] = Zb[base + p];
  }
  __syncthreads();

#define DD_DECL(i) float dd##i = 1e10f;
  REP8(DD_DECL)
#undef DD_DECL

  int far = 0;
  for (int it = 0; ; ++it){
    if (sub == 0 && t == 0){
      float cx = Xb[far], cy = Yb[far], cz = Zb[far];
      float* cw = g_center  + (size_t)(b*GG + it)*3;
      float* co = outCenter + (size_t)(b*GG + it)*3;
      cw[0] = cx; cw[1] = cy; cw[2] = cz;
      co[0] = cx; co[1] = cy; co[2] = cz;
    }
    if (it == GG - 1) break;

    float cx = Xb[far], cy = Yb[far], cz = Zb[far];
    unsigned long long bk = 0ull;
#define DD_UPD(i) { \
    int p = (i << 9) + t; \
    float dx = rn_sub(sx[p], cx); \
    float dy = rn_sub(sy[p], cy); \
    float dz = rn_sub(szz[p], cz); \
    float s_ = rn_add(rn_add(rn_mul(dx,dx), rn_mul(dy,dy)), rn_mul(dz,dz)); \
    float d_ = fminf(dd##i, s_); \
    dd##i = d_; \
    unsigned long long k_ = ((unsigned long long)fkey(d_) << 32) \
                          | (unsigned)(0xFFFFFFFFu - (unsigned)(base + p)); \
    if (k_ > bk) bk = k_; }
    REP8(DD_UPD)
#undef DD_UPD

    #pragma unroll
    for (int off = 32; off >= 1; off >>= 1){
      unsigned long long o = (unsigned long long)__shfl_xor((long long)bk, off);
      if (o > bk) bk = o;
    }
    if (ln == 0) skey[wv] = bk;
    __syncthreads();
    if (wv == 0){
      unsigned long long m = (ln < 8) ? skey[ln] : 0ull;
      #pragma unroll
      for (int off = 1; off <= 4; off <<= 1){
        unsigned long long o = (unsigned long long)__shfl_xor((long long)m, off);
        if (o > m) m = o;
      }
      if (ln == 0)
        __hip_atomic_store(&g_part[(((b << 3) + sub) << 6) + it], m,
                           __ATOMIC_RELAXED, __HIP_MEMORY_SCOPE_AGENT);
      unsigned long long k = 0ull;
      if (ln < 8){
        unsigned long long* p = &g_part[(((b << 3) + ln) << 6) + it];
        do {
          k = __hip_atomic_load(p, __ATOMIC_RELAXED, __HIP_MEMORY_SCOPE_AGENT);
        } while (k == 0ull);
      }
      #pragma unroll
      for (int off = 1; off <= 4; off <<= 1){
        unsigned long long o = (unsigned long long)__shfl_xor((long long)k, off);
        if (o > k) k = o;
      }
      if (ln == 0) s_far = (int)(0xFFFFFFFFu - (unsigned)(k & 0xFFFFFFFFu));
    }
    __syncthreads();
    far = s_far;
  }
}

// ---------------------------------------------------------------------------
// KNN v6: 4 centers/block, 512 blocks (2 blocks/CU, 8 waves/CU).
// r13 failed at 8 centers/256 blocks because occupancy = 1 wave/SIMD exposed
// all load latency. This keeps r13's traffic amortization (2GB -> 512MB)
// at restored occupancy. Per-center math is BIT-IDENTICAL to validated v4:
// top-2 track -> per-wave bitonic -> exact 16th-of-256 T -> collect <=T ->
// exact (d2,idx) sort. Wave w owns center w for T + selection.
// XCD co-location: batch b's 16 blocks all == b (mod 8).
// ---------------------------------------------------------------------------
__global__ __launch_bounds__(256) void k_knn(void){
  const int j  = blockIdx.x;                    // 0..511
  const int b  = (j & 7) + ((j >> 7) << 3);     // batch 0..31
  const int g0 = ((j >> 3) & 15) << 2;          // first of 4 centers
  const int t  = threadIdx.x;
  const int w  = t >> 6;                        // wave 0..3
  const int ln = t & 63;
  const float4* X4 = (const float4*)(g_X  + (size_t)b*NN);
  const float4* Y4 = (const float4*)(g_Y  + (size_t)b*NN);
  const float4* Z4 = (const float4*)(g_Z  + (size_t)b*NN);
  const float4* N4 = (const float4*)(g_N2 + (size_t)b*NN);

  __shared__ float sC[4][4];                    // cx,cy,cz,cn2 per center
  __shared__ unsigned sE[4][64];                // per-center 4x16 wave mins
  __shared__ unsigned sTk[4];
  __shared__ unsigned long long cand[4][512];   // 16 KB
  __shared__ int cnt[4];

  if (t < 4){
    const float* cp = g_center + (size_t)(b*GG + g0 + t)*3;
    float x = cp[0], y = cp[1], z = cp[2];
    sC[0][t] = x; sC[1][t] = y; sC[2][t] = z;
    sC[3][t] = rn_add(rn_add(rn_mul(x,x), rn_mul(y,y)), rn_mul(z,z));
    cnt[t] = 0;
  }
  __syncthreads();

  float cx[4], cy[4], cz[4], cn[4];
  #pragma unroll
  for (int c = 0; c < 4; ++c){
    cx[c] = sC[0][c]; cy[c] = sC[1][c]; cz[c] = sC[2][c]; cn[c] = sC[3][c];
  }

  // ---- pass 1: per-center top-2 over this thread's 128 points ----
  float e0[4], e1[4];
  #pragma unroll
  for (int c = 0; c < 4; ++c){ e0[c] = INFINITY; e1[c] = INFINITY; }
  #pragma unroll 2
  for (int s = 0; s < 32; ++s){
    int q = (s << 8) + t;
    float4 x = X4[q], y = Y4[q], z = Z4[q], n = N4[q];
    #pragma unroll
    for (int c = 0; c < 4; ++c){
      #define P1C(comp) { \
        float e = rn_add(rn_add(rn_mul(cx[c],x.comp), rn_mul(cy[c],y.comp)), rn_mul(cz[c],z.comp)); \
        float d = rn_sub(rn_add(cn[c], n.comp), rn_add(e,e)); \
        float nm2 = fminf(e1[c], fmaxf(e0[c], d)); \
        e0[c] = fminf(e0[c], d); \
        e1[c] = nm2; }
      P1C(x) P1C(y) P1C(z) P1C(w)
      #undef P1C
    }
  }

  // ---- per-wave bitonic sort of e1-keys per center; 16 smallest -> sE ----
  #pragma unroll
  for (int c = 0; c < 4; ++c){
    unsigned v = fkey(e1[c]);
    #pragma unroll
    for (int k = 2; k <= 64; k <<= 1){
      #pragma unroll
      for (int jj = k >> 1; jj > 0; jj >>= 1){
        unsigned o = (unsigned)__shfl_xor((int)v, jj);
        bool keepmin = (((ln & k) == 0) == ((ln & jj) == 0));
        unsigned mn = o < v ? o : v;
        unsigned mx = o < v ? v : o;
        v = keepmin ? mn : mx;
      }
    }
    if (ln < 16) sE[c][w*16 + ln] = v;
  }
  __syncthreads();

  // ---- T for center w (this wave): exact 16th smallest of 256 e1s ----
  {
    unsigned v = sE[w][ln];
    #pragma unroll
    for (int k = 2; k <= 64; k <<= 1){
      #pragma unroll
      for (int jj = k >> 1; jj > 0; jj >>= 1){
        unsigned o = (unsigned)__shfl_xor((int)v, jj);
        bool keepmin = (((ln & k) == 0) == ((ln & jj) == 0));
        unsigned mn = o < v ? o : v;
        unsigned mx = o < v ? v : o;
        v = keepmin ? mn : mx;
      }
    }
    unsigned T = (unsigned)__shfl((int)v, 15);
    if (ln == 0) sTk[w] = T;
  }
  __syncthreads();

  unsigned Tr[4];
  #pragma unroll
  for (int c = 0; c < 4; ++c) Tr[c] = sTk[c];

  // ---- pass 2: collect candidates per center ----
  #pragma unroll 2
  for (int s = 0; s < 32; ++s){
    int q = (s << 8) + t;
    float4 x = X4[q], y = Y4[q], z = Z4[q], n = N4[q];
    #pragma unroll
    for (int c = 0; c < 4; ++c){
      #define P2C(comp, kk) { \
        float e = rn_add(rn_add(rn_mul(cx[c],x.comp), rn_mul(cy[c],y.comp)), rn_mul(cz[c],z.comp)); \
        float d = rn_sub(rn_add(cn[c], n.comp), rn_add(e,e)); \
        unsigned fk = fkey(d); \
        if (fk <= Tr[c]){ \
          int p = atomicAdd(&cnt[c], 1); \
          if (p < 512) \
            cand[c][p] = ((unsigned long long)fk << 32) | (unsigned)((q<<2)+kk); } }
      P2C(x,0) P2C(y,1) P2C(z,2) P2C(w,3)
      #undef P2C
    }
  }
  __syncthreads();

  // ---- selection: wave w -> center w; exact (d2, idx) order ----
  {
    int C = cnt[w]; if (C > 512) C = 512;
    int* kout = g_knn + (size_t)(b*GG + g0 + w)*KK;
    if (C <= 64){
      unsigned long long kk = (ln < C) ? cand[w][ln] : ~0ull;
      #pragma unroll
      for (int k = 2; k <= 64; k <<= 1){
        #pragma unroll
        for (int jj = k >> 1; jj > 0; jj >>= 1){
          unsigned long long o = (unsigned long long)__shfl_xor((long long)kk, jj);
          bool keepmin = (((ln & k) == 0) == ((ln & jj) == 0));
          unsigned long long mn = o < kk ? o : kk;
          unsigned long long mx = o < kk ? kk : o;
          kk = keepmin ? mn : mx;
        }
      }
      if (ln < KK) kout[ln] = (int)(kk & 0xffffffffu);
    } else {
      unsigned long long md[8];
      #pragma unroll
      for (int jj = 0; jj < 8; ++jj){
        int e = ln + (jj << 6);
        md[jj] = (e < C) ? cand[w][e] : ~0ull;
      }
      for (int r = 0; r < KK; ++r){
        unsigned long long bk = md[0];
        #pragma unroll
        for (int jj = 1; jj < 8; ++jj) if (md[jj] < bk) bk = md[jj];
        #pragma unroll
        for (int off = 32; off >= 1; off >>= 1){
          unsigned long long o = (unsigned long long)__shfl_xor((long long)bk, off);
          if (o < bk) bk = o;
        }
        #pragma unroll
        for (int jj = 0; jj < 8; ++jj) if (md[jj] == bk) md[jj] = ~0ull;
        if (ln == 0) kout[r] = (int)(bk & 0xffffffffu);
      }
    }
  }
}

// ---------------------------------------------------------------------------
// MLP v2 (validated r12): L1 VALU; L2/L3 mfma_f32_16x16x32_bf16.
// ---------------------------------------------------------------------------
__global__ __launch_bounds__(256) void k_mlp(const float* __restrict__ xyz,
                                             const float* __restrict__ feat,
                                             float* __restrict__ outPatch){
  const int bg = blockIdx.x;
  const int b  = bg >> 6;
  const int t  = threadIdx.x;
  const int w  = t >> 6;
  const int ln = t & 63;
  const float* xb = xyz  + (size_t)b*NN*3;
  const float* fb = feat + (size_t)b*NN*3;

  __shared__ float h0[KK][8];
  __shared__ __align__(16) unsigned short h1b[KK][72];
  __shared__ __align__(16) unsigned short h2b[KK][136];

  if (t < KK){
    int idx = g_knn[(size_t)bg*KK + t] & (NN - 1);
    const float* cp = g_center + (size_t)bg*3;
    h0[t][0] = rn_sub(xb[idx*3+0], cp[0]);
    h0[t][1] = rn_sub(xb[idx*3+1], cp[1]);
    h0[t][2] = rn_sub(xb[idx*3+2], cp[2]);
    h0[t][3] = fb[idx*3+0];
    h0[t][4] = fb[idx*3+1];
    h0[t][5] = fb[idx*3+2];
  }
  __syncthreads();

  {
    int p = t >> 3, ob = (t & 7) * 8;
    float acc[8];
    #pragma unroll
    for (int j = 0; j < 8; ++j) acc[j] = g_b1[ob + j];
    #pragma unroll
    for (int c = 0; c < 6; ++c){
      float a = h0[p][c];
      const float4* wr = (const float4*)(g_w1t + c*64 + ob);
      float4 wa = wr[0], wb = wr[1];
      acc[0] = fmaf(a, wa.x, acc[0]); acc[1] = fmaf(a, wa.y, acc[1]);
      acc[2] = fmaf(a, wa.z, acc[2]); acc[3] = fmaf(a, wa.w, acc[3]);
      acc[4] = fmaf(a, wb.x, acc[4]); acc[5] = fmaf(a, wb.y, acc[5]);
      acc[6] = fmaf(a, wb.z, acc[6]); acc[7] = fmaf(a, wb.w, acc[7]);
    }
    short8 v;
    #pragma unroll
    for (int j = 0; j < 8; ++j) v[j] = (short)f2bf(fmaxf(acc[j], 0.f));
    *reinterpret_cast<short8*>(&h1b[p][ob]) = v;
  }
  __syncthreads();

  {
    f32x4 a00 = {0,0,0,0}, a01 = {0,0,0,0}, a10 = {0,0,0,0}, a11 = {0,0,0,0};
    const int g8 = (ln >> 4) << 3;
    #pragma unroll
    for (int kk = 0; kk < 2; ++kk){
      short8 A0 = *reinterpret_cast<const short8*>(&h1b[(ln & 15)][kk*32 + g8]);
      short8 A1 = *reinterpret_cast<const short8*>(&h1b[16 + (ln & 15)][kk*32 + g8]);
      short8 B0 = *reinterpret_cast<const short8*>(&g_w2f[(((2*w+0)*2 + kk)*64 + ln)*8]);
      short8 B1 = *reinterpret_cast<const short8*>(&g_w2f[(((2*w+1)*2 + kk)*64 + ln)*8]);
      a00 = __builtin_amdgcn_mfma_f32_16x16x32_bf16(A0, B0, a00, 0, 0, 0);
      a01 = __builtin_amdgcn_mfma_f32_16x16x32_bf16(A1, B0, a01, 0, 0, 0);
      a10 = __builtin_amdgcn_mfma_f32_16x16x32_bf16(A0, B1, a10, 0, 0, 0);
      a11 = __builtin_amdgcn_mfma_f32_16x16x32_bf16(A1, B1, a11, 0, 0, 0);
    }
    int col0 = (2*w)*16 + (ln & 15);
    int col1 = col0 + 16;
    float bz0 = g_b2[col0], bz1 = g_b2[col1];
    int r0 = (ln >> 4) << 2;
    #pragma unroll
    for (int r = 0; r < 4; ++r){
      h2b[r0 + r][col0]      = f2bf(fmaxf(a00[r] + bz0, 0.f));
      h2b[16 + r0 + r][col0] = f2bf(fmaxf(a01[r] + bz0, 0.f));
      h2b[r0 + r][col1]      = f2bf(fmaxf(a10[r] + bz1, 0.f));
      h2b[16 + r0 + r][col1] = f2bf(fmaxf(a11[r] + bz1, 0.f));
    }
  }
  __syncthreads();

  {
    f32x4 acc3[6][2];
    #pragma unroll
    for (int ci = 0; ci < 6; ++ci){
      acc3[ci][0] = (f32x4){0,0,0,0};
      acc3[ci][1] = (f32x4){0,0,0,0};
    }
    const int g8 = (ln >> 4) << 3;
    #pragma unroll
    for (int kk = 0; kk < 4; ++kk){
      short8 A0 = *reinterpret_cast<const short8*>(&h2b[(ln & 15)][kk*32 + g8]);
      short8 A1 = *reinterpret_cast<const short8*>(&h2b[16 + (ln & 15)][kk*32 + g8]);
      #pragma unroll
      for (int ci = 0; ci < 6; ++ci){
        int ct = w*6 + ci;
        short8 B = *reinterpret_cast<const short8*>(&g_w3f[((ct*4 + kk)*64 + ln)*8]);
        acc3[ci][0] = __builtin_amdgcn_mfma_f32_16x16x32_bf16(A0, B, acc3[ci][0], 0, 0, 0);
        acc3[ci][1] = __builtin_amdgcn_mfma_f32_16x16x32_bf16(A1, B, acc3[ci][1], 0, 0, 0);
      }
    }
    #pragma unroll
    for (int ci = 0; ci < 6; ++ci){
      float m = acc3[ci][0][0];
      #pragma unroll
      for (int r = 1; r < 4; ++r) m = fmaxf(m, acc3[ci][0][r]);
      #pragma unroll
      for (int r = 0; r < 4; ++r) m = fmaxf(m, acc3[ci][1][r]);
      m = fmaxf(m, __shfl_xor(m, 16));
      m = fmaxf(m, __shfl_xor(m, 32));
      if (ln < 16){
        int col = (w*6 + ci)*16 + ln;
        outPatch[(size_t)bg*DD + col] = m + g_b3[col];
      }
    }
  }
}

// ---------------------------------------------------------------------------
extern "C" void kernel_launch(void* const* d_in, const int* in_sizes, int n_in,
                              void* d_out, int out_size, void* d_ws, size_t ws_size,
                              hipStream_t stream){
  (void)in_sizes; (void)n_in; (void)out_size; (void)d_ws; (void)ws_size;
  const float* xyz  = (const float*)d_in[0];
  const float* feat = (const float*)d_in[1];
  const float* w1 = (const float*)d_in[2];
  const float* g1 = (const float*)d_in[3];
  const float* b1 = (const float*)d_in[4];
  const float* m1 = (const float*)d_in[5];
  const float* v1 = (const float*)d_in[6];
  const float* w2 = (const float*)d_in[7];
  const float* g2 = (const float*)d_in[8];
  const float* b2 = (const float*)d_in[9];
  const float* m2 = (const float*)d_in[10];
  const float* v2 = (const float*)d_in[11];
  const float* w3 = (const float*)d_in[12];
  const float* g3 = (const float*)d_in[13];
  const float* b3 = (const float*)d_in[14];
  const float* m3 = (const float*)d_in[15];
  const float* v3 = (const float*)d_in[16];
  float* out = (float*)d_out;

  k_prep<<<64, 256, 0, stream>>>(w1,g1,b1,m1,v1, w2,g2,b2,m2,v2, w3,g3,b3,m3,v3);
  k_soa<<<(BB*NN)/256, 256, 0, stream>>>(xyz);
  k_zero<<<64, 256, 0, stream>>>();
  k_fps<<<BB*FPS_NBLK, 512, 0, stream>>>(out);
  k_knn<<<512, 256, 0, stream>>>();
  k_mlp<<<BB*GG, 256, 0, stream>>>(xyz, feat, out + (size_t)BB*GG*3);
}